// Round 1
// baseline (224.209 us; speedup 1.0000x reference)
//
#include <hip/hip_runtime.h>
#include <hip/hip_bf16.h>

#define EMBED 512
#define NH 8
#define DH 64
#define NSEQ 2048
#define BATCH 2
#define NROWS (BATCH * NSEQ)     // 4096
#define QKV_STRIDE 1536          // Q | K | V concatenated along columns

// ---------------------------------------------------------------------------
// Tiled fp32 GEMM core: C[m0:m0+64, n0:n0+64] = A[M,512] @ W[N,512]^T + bias
// A row-major lda=512 (k contiguous), W row-major (k contiguous).
// 256 threads, 4x4 microtile, BK=16, k-major LDS so inner reads are float4.
// ---------------------------------------------------------------------------
__device__ __forceinline__ void gemm_tile_64x64(
    const float* __restrict__ A, int lda,
    const float* __restrict__ W,
    const float* __restrict__ bias, int nbias,   // bias indexed by local n
    float* __restrict__ C, int ldc, int m0, int n0_local, int n0_store)
{
    __shared__ float As[16][68];   // [k][m], pad to 68 floats (16B-aligned rows)
    __shared__ float Bs[16][68];   // [k][n]

    const int t  = threadIdx.x;
    const int tx = t & 15;         // n-direction
    const int ty = t >> 4;         // m-direction
    const int lrow = t >> 2;       // 0..63 staging row
    const int lk4  = (t & 3) << 2; // 0,4,8,12 staging k offset

    float acc[4][4];
#pragma unroll
    for (int i = 0; i < 4; ++i)
#pragma unroll
        for (int j = 0; j < 4; ++j) acc[i][j] = 0.f;

    const float* Arow = A + (size_t)(m0 + lrow) * lda + lk4;
    const float* Brow = W + (size_t)(n0_local + lrow) * EMBED + lk4;

    for (int kc = 0; kc < EMBED; kc += 16) {
        float4 av = *(const float4*)(Arow + kc);
        float4 bv = *(const float4*)(Brow + kc);
        As[lk4 + 0][lrow] = av.x; As[lk4 + 1][lrow] = av.y;
        As[lk4 + 2][lrow] = av.z; As[lk4 + 3][lrow] = av.w;
        Bs[lk4 + 0][lrow] = bv.x; Bs[lk4 + 1][lrow] = bv.y;
        Bs[lk4 + 2][lrow] = bv.z; Bs[lk4 + 3][lrow] = bv.w;
        __syncthreads();
#pragma unroll
        for (int kk = 0; kk < 16; ++kk) {
            float4 af = *(const float4*)&As[kk][ty * 4];
            float4 bf = *(const float4*)&Bs[kk][tx * 4];
            float a[4] = {af.x, af.y, af.z, af.w};
            float b[4] = {bf.x, bf.y, bf.z, bf.w};
#pragma unroll
            for (int i = 0; i < 4; ++i)
#pragma unroll
                for (int j = 0; j < 4; ++j)
                    acc[i][j] = fmaf(a[i], b[j], acc[i][j]);
        }
        __syncthreads();
    }

    float bj[4];
#pragma unroll
    for (int j = 0; j < 4; ++j) bj[j] = bias[nbias + tx * 4 + j];

#pragma unroll
    for (int i = 0; i < 4; ++i) {
        const int m = m0 + ty * 4 + i;
        float4 o;
        o.x = acc[i][0] + bj[0];
        o.y = acc[i][1] + bj[1];
        o.z = acc[i][2] + bj[2];
        o.w = acc[i][3] + bj[3];
        *(float4*)(C + (size_t)m * ldc + n0_store + tx * 4) = o;
    }
}

// Fused QKV: grid (M/64=64, 1536/64=24). Column block selects Wq/Wk/Wv.
__global__ __launch_bounds__(256) void gemm_qkv(
    const float* __restrict__ X,
    const float* __restrict__ Wq, const float* __restrict__ bq,
    const float* __restrict__ Wk, const float* __restrict__ bk,
    const float* __restrict__ Wv, const float* __restrict__ bv,
    float* __restrict__ QKV)
{
    const int m0  = blockIdx.x * 64;
    const int n0g = blockIdx.y * 64;     // 0..1535
    const int sel = n0g >> 9;            // 0:Q 1:K 2:V
    const int n0  = n0g & 511;
    const float* W    = (sel == 0) ? Wq : (sel == 1) ? Wk : Wv;
    const float* bias = (sel == 0) ? bq : (sel == 1) ? bk : bv;
    gemm_tile_64x64(X, EMBED, W, bias, n0, QKV, QKV_STRIDE, m0, n0, n0g);
}

// Output projection: grid (64, 8)
__global__ __launch_bounds__(256) void gemm_out(
    const float* __restrict__ A, const float* __restrict__ Wo,
    const float* __restrict__ bo, float* __restrict__ C)
{
    const int m0 = blockIdx.x * 64;
    const int n0 = blockIdx.y * 64;
    gemm_tile_64x64(A, EMBED, Wo, bo, n0, C, EMBED, m0, n0, n0);
}

// ---------------------------------------------------------------------------
// V tail sum partials: Vsum[b,h,d] = sum_{j=3..2047} V[b,h,j,d]
// grid (B*H=16, 16 chunks), 64 threads. chunk covers 128 rows.
// ---------------------------------------------------------------------------
__global__ __launch_bounds__(64) void vsum_part(
    const float* __restrict__ QKV, float* __restrict__ vpart)
{
    const int bh = blockIdx.x;
    const int c  = blockIdx.y;
    const int b = bh >> 3, h = bh & 7;
    const int lane = threadIdx.x;
    const float* Vb = QKV + (size_t)(b * NSEQ) * QKV_STRIDE + 1024 + h * DH + lane;
    const int j0 = (c * 128 < 3) ? 3 : c * 128;
    const int j1 = c * 128 + 128;
    float s = 0.f;
#pragma unroll 4
    for (int j = j0; j < j1; ++j) s += Vb[(size_t)j * QKV_STRIDE];
    vpart[(bh * 16 + c) * 64 + lane] = s;
}

// ---------------------------------------------------------------------------
// Attention: wave-per-row. lane = d (0..63).
// grid (B*H=16, 32), block 256 (4 waves), each wave does 16 rows.
// ---------------------------------------------------------------------------
__global__ __launch_bounds__(256) void attn_kernel(
    const float* __restrict__ QKV, const float* __restrict__ vpart,
    float* __restrict__ AO)
{
    const int bh = blockIdx.x;
    const int b = bh >> 3, h = bh & 7;
    const int wave = threadIdx.x >> 6;
    const int lane = threadIdx.x & 63;

    const float* Qb = QKV + (size_t)(b * NSEQ) * QKV_STRIDE + h * DH;
    const float* Kb = Qb + 512;
    const float* Vb = Qb + 1024;

    // per-lane fixed V rows 0,1,2 and the tail sum
    const float v0 = Vb[(size_t)0 * QKV_STRIDE + lane];
    const float v1 = Vb[(size_t)1 * QKV_STRIDE + lane];
    const float v2 = Vb[(size_t)2 * QKV_STRIDE + lane];
    float vs = 0.f;
#pragma unroll
    for (int c = 0; c < 16; ++c) vs += vpart[(bh * 16 + c) * 64 + lane];

    float* AOb = AO + (size_t)(b * NSEQ) * EMBED + h * DH;
    const int r0 = blockIdx.y * 64 + wave * 16;

    for (int i = 0; i < 16; ++i) {
        const int r = r0 + i;
        const float q  = Qb[(size_t)r * QKV_STRIDE + lane];
        const float km = Kb[(size_t)r * QKV_STRIDE + lane];
        const float kp = (r > 0)        ? Kb[(size_t)(r - 1) * QKV_STRIDE + lane] : 0.f;
        const float kn = (r < NSEQ - 1) ? Kb[(size_t)(r + 1) * QKV_STRIDE + lane] : 0.f;
        float s0 = q * kp, s1 = q * km, s2 = q * kn;
#pragma unroll
        for (int off = 32; off > 0; off >>= 1) {
            s0 += __shfl_xor(s0, off);
            s1 += __shfl_xor(s1, off);
            s2 += __shfl_xor(s2, off);
        }
        const float m  = fmaxf(fmaxf(s0, s1), fmaxf(s2, 0.f));
        const float e0 = __expf(s0 - m);
        const float e1 = __expf(s1 - m);
        const float e2 = __expf(s2 - m);
        const float eb = __expf(-m);
        const float rd = 1.f / (e0 + e1 + e2 + (float)(NSEQ - 3) * eb);
        const float o  = (e0 * v0 + e1 * v1 + e2 * v2 + eb * vs) * rd;
        AOb[(size_t)r * EMBED + lane] = o;
    }
}

extern "C" void kernel_launch(void* const* d_in, const int* in_sizes, int n_in,
                              void* d_out, int out_size, void* d_ws, size_t ws_size,
                              hipStream_t stream)
{
    const float* x  = (const float*)d_in[0];
    const float* Wq = (const float*)d_in[1];
    const float* bq = (const float*)d_in[2];
    const float* Wk = (const float*)d_in[3];
    const float* bk = (const float*)d_in[4];
    const float* Wv = (const float*)d_in[5];
    const float* bv = (const float*)d_in[6];
    const float* Wo = (const float*)d_in[7];
    const float* bo = (const float*)d_in[8];
    float* out = (float*)d_out;

    float* QKV   = (float*)d_ws;                          // 4096*1536
    float* AO    = QKV + (size_t)NROWS * QKV_STRIDE;      // 4096*512
    float* vpart = AO + (size_t)NROWS * EMBED;            // 16*16*64

    gemm_qkv<<<dim3(64, 24), 256, 0, stream>>>(x, Wq, bq, Wk, bk, Wv, bv, QKV);
    vsum_part<<<dim3(16, 16), 64, 0, stream>>>(QKV, vpart);
    attn_kernel<<<dim3(16, 32), 256, 0, stream>>>(QKV, vpart, AO);
    gemm_out<<<dim3(64, 8), 256, 0, stream>>>(AO, Wo, bo, out);
}

// Round 2
// 123.933 us; speedup vs baseline: 1.8091x; 1.8091x over previous
//
#include <hip/hip_runtime.h>
#include <hip/hip_bf16.h>

#define EMBED 512
#define NH 8
#define DH 64
#define NSEQ 2048
#define BATCH 2
#define NROWS (BATCH * NSEQ)     // 4096
#define QKV_STRIDE 1536

typedef unsigned short u16;
typedef __bf16 bf16x8 __attribute__((ext_vector_type(8)));
typedef float f32x4 __attribute__((ext_vector_type(4)));

__device__ __forceinline__ u16 f2bf(float f) {
    unsigned u = __float_as_uint(f);
    unsigned r = (u + 0x7FFFu + ((u >> 16) & 1u)) >> 16;
    return (u16)r;
}

// ---------------------------------------------------------------------------
// prep: x -> xb (bf16), Wq|Wk|Wv -> Wcat[1536][512] bf16, Wo -> Wob bf16.
// Flat index, 8 elems/thread, all segment boundaries divisible by 8.
// ---------------------------------------------------------------------------
#define XELEMS   (NROWS * EMBED)          // 2097152
#define WCATELEMS (1536 * EMBED)          // 786432
#define WOELEMS  (EMBED * EMBED)          // 262144

__global__ __launch_bounds__(256) void prep_kernel(
    const float* __restrict__ x,
    const float* __restrict__ Wq, const float* __restrict__ Wk,
    const float* __restrict__ Wv, const float* __restrict__ Wo,
    u16* __restrict__ xb, u16* __restrict__ Wcat, u16* __restrict__ Wob)
{
    const long long e0 = (long long)(blockIdx.x * 256 + threadIdx.x) * 8;
    const float* src;
    u16* dst;
    if (e0 < XELEMS) {
        src = x + e0; dst = xb + e0;
    } else if (e0 < XELEMS + WCATELEMS) {
        const long long j = e0 - XELEMS;
        const int row = (int)(j >> 9);       // 0..1535 in Wcat
        const int col = (int)(j & 511);
        const int sel = row >> 9;            // 0:Wq 1:Wk 2:Wv
        const int r   = row & 511;
        const float* W = (sel == 0) ? Wq : (sel == 1) ? Wk : Wv;
        src = W + (size_t)r * EMBED + col; dst = Wcat + j;
    } else {
        const long long j = e0 - XELEMS - WCATELEMS;
        src = Wo + j; dst = Wob + j;
    }
    float4 a = *(const float4*)(src);
    float4 b = *(const float4*)(src + 4);
    union { u16 u[8]; uint4 v; } p;
    p.u[0] = f2bf(a.x); p.u[1] = f2bf(a.y); p.u[2] = f2bf(a.z); p.u[3] = f2bf(a.w);
    p.u[4] = f2bf(b.x); p.u[5] = f2bf(b.y); p.u[6] = f2bf(b.z); p.u[7] = f2bf(b.w);
    *(uint4*)(dst) = p.v;
}

// ---------------------------------------------------------------------------
// bf16 MFMA GEMM tile: C[m0:+128, n0c:+128] = A @ W^T + bias (fp32 out).
// A[M][512] bf16 k-major, W[N][512] bf16 k-major (B^T form).
// 256 threads = 4 waves (2x2 of 64x64), 16x16x32 MFMA, BK=32,
// global_load_lds width=16 staging (wave-uniform base + lane*16).
// ---------------------------------------------------------------------------
__device__ __forceinline__ void gemm_tile_128(
    const u16* __restrict__ A, const u16* __restrict__ W,
    const float* __restrict__ bias,   // indexed by tile-local col 0..127
    float* __restrict__ C, int ldc, int m0, int n0w, int n0c)
{
    __shared__ u16 As[128 * 32];
    __shared__ u16 Bs[128 * 32];

    const int t    = threadIdx.x;
    const int wave = t >> 6, lane = t & 63;
    const int wm   = wave >> 1, wn = wave & 1;
    const int qd   = lane >> 4, lr = lane & 15;

    f32x4 acc[4][4] = {};

    const u16* Ag = A + (size_t)m0 * EMBED;
    const u16* Wg = W + (size_t)n0w * EMBED;
    const int srow = t >> 2;        // 0..63
    const int sk   = (t & 3) * 8;

    // wave-uniform LDS bases (elems): load0 rows 0..63, load1 rows 64..127
    u16* AsW0 = As + (size_t)(wave * 64) * 8;
    u16* AsW1 = As + (size_t)(256 + wave * 64) * 8;
    u16* BsW0 = Bs + (size_t)(wave * 64) * 8;
    u16* BsW1 = Bs + (size_t)(256 + wave * 64) * 8;

    for (int kc = 0; kc < EMBED; kc += 32) {
        __builtin_amdgcn_global_load_lds(
            (const __attribute__((address_space(1))) void*)(Ag + (size_t)srow * EMBED + kc + sk),
            (__attribute__((address_space(3))) void*)AsW0, 16, 0, 0);
        __builtin_amdgcn_global_load_lds(
            (const __attribute__((address_space(1))) void*)(Ag + (size_t)(srow + 64) * EMBED + kc + sk),
            (__attribute__((address_space(3))) void*)AsW1, 16, 0, 0);
        __builtin_amdgcn_global_load_lds(
            (const __attribute__((address_space(1))) void*)(Wg + (size_t)srow * EMBED + kc + sk),
            (__attribute__((address_space(3))) void*)BsW0, 16, 0, 0);
        __builtin_amdgcn_global_load_lds(
            (const __attribute__((address_space(1))) void*)(Wg + (size_t)(srow + 64) * EMBED + kc + sk),
            (__attribute__((address_space(3))) void*)BsW1, 16, 0, 0);
        __syncthreads();

        bf16x8 af[4], bfr[4];
#pragma unroll
        for (int i = 0; i < 4; ++i) {
            af[i]  = *(const bf16x8*)&As[(wm * 64 + i * 16 + lr) * 32 + qd * 8];
            bfr[i] = *(const bf16x8*)&Bs[(wn * 64 + i * 16 + lr) * 32 + qd * 8];
        }
#pragma unroll
        for (int mi = 0; mi < 4; ++mi)
#pragma unroll
            for (int ni = 0; ni < 4; ++ni)
                acc[mi][ni] = __builtin_amdgcn_mfma_f32_16x16x32_bf16(
                    af[mi], bfr[ni], acc[mi][ni], 0, 0, 0);
        __syncthreads();
    }

    // epilogue: C/D layout col=lane&15, row=(lane>>4)*4+reg
#pragma unroll
    for (int ni = 0; ni < 4; ++ni) {
        const int cl = wn * 64 + ni * 16 + lr;
        const float bv = bias[cl];
        const int col = n0c + cl;
#pragma unroll
        for (int mi = 0; mi < 4; ++mi) {
#pragma unroll
            for (int e = 0; e < 4; ++e) {
                const int row = m0 + wm * 64 + mi * 16 + qd * 4 + e;
                C[(size_t)row * ldc + col] = acc[mi][ni][e] + bv;
            }
        }
    }
}

// QKV GEMM: grid (32, 12). Wcat rows 0..511=Wq, 512..1023=Wk, 1024..1535=Wv.
__global__ __launch_bounds__(256) void gemm_qkv_mfma(
    const u16* __restrict__ xb, const u16* __restrict__ Wcat,
    const float* __restrict__ bq, const float* __restrict__ bk,
    const float* __restrict__ bv, float* __restrict__ QKV)
{
    const int m0 = blockIdx.x * 128;
    const int n0 = blockIdx.y * 128;
    const int sel = n0 >> 9;
    const float* bias = ((sel == 0) ? bq : (sel == 1) ? bk : bv) + (n0 & 511);
    gemm_tile_128(xb, Wcat, bias, QKV, QKV_STRIDE, m0, n0, n0);
}

// Output GEMM: grid (32, 4).
__global__ __launch_bounds__(256) void gemm_out_mfma(
    const u16* __restrict__ AOb, const u16* __restrict__ Wob,
    const float* __restrict__ bo, float* __restrict__ C)
{
    const int m0 = blockIdx.x * 128;
    const int n0 = blockIdx.y * 128;
    gemm_tile_128(AOb, Wob, bo + n0, C, EMBED, m0, n0, n0);
}

// ---------------------------------------------------------------------------
// V full-sum partials: vpart[bh][c*4+w][d] = sum over 64 rows of V[b,h,j,d]
// grid (16, 8), 256 threads (4 waves x 64 rows each).
// ---------------------------------------------------------------------------
__global__ __launch_bounds__(256) void vsum_part(
    const float* __restrict__ QKV, float* __restrict__ vpart)
{
    const int bh = blockIdx.x;
    const int b = bh >> 3, h = bh & 7;
    const int wave = threadIdx.x >> 6, lane = threadIdx.x & 63;
    const float* Vb = QKV + (size_t)(b * NSEQ) * QKV_STRIDE + 1024 + h * DH + lane;
    const int j0 = blockIdx.y * 256 + wave * 64;
    float s = 0.f;
#pragma unroll 8
    for (int j = j0; j < j0 + 64; ++j) s += Vb[(size_t)j * QKV_STRIDE];
    vpart[(size_t)(bh * 32 + blockIdx.y * 4 + wave) * 64 + lane] = s;
}

// ---------------------------------------------------------------------------
// Attention: wave per 4 rows. lane = d. grid (16, 128), block 256.
// Writes AO directly as bf16 for the output GEMM.
// ---------------------------------------------------------------------------
__global__ __launch_bounds__(256) void attn_kernel(
    const float* __restrict__ QKV, const float* __restrict__ vpart,
    u16* __restrict__ AOb)
{
    const int bh = blockIdx.x;
    const int b = bh >> 3, h = bh & 7;
    const int wave = threadIdx.x >> 6, lane = threadIdx.x & 63;

    const float* Qb = QKV + (size_t)(b * NSEQ) * QKV_STRIDE + h * DH;
    const float* Kb = Qb + 512;
    const float* Vb = Qb + 1024;

    const float v0 = Vb[(size_t)0 * QKV_STRIDE + lane];
    const float v1 = Vb[(size_t)1 * QKV_STRIDE + lane];
    const float v2 = Vb[(size_t)2 * QKV_STRIDE + lane];
    float vs = 0.f;
#pragma unroll
    for (int c = 0; c < 32; ++c) vs += vpart[(size_t)(bh * 32 + c) * 64 + lane];
    vs -= (v0 + v1 + v2);   // tail = sum_{j>=3}

    u16* AObh = AOb + (size_t)(b * NSEQ) * EMBED + h * DH;
    const int r0 = blockIdx.y * 16 + wave * 4;

#pragma unroll
    for (int i = 0; i < 4; ++i) {
        const int r = r0 + i;
        const float q  = Qb[(size_t)r * QKV_STRIDE + lane];
        const float km = Kb[(size_t)r * QKV_STRIDE + lane];
        const float kp = (r > 0)        ? Kb[(size_t)(r - 1) * QKV_STRIDE + lane] : 0.f;
        const float kn = (r < NSEQ - 1) ? Kb[(size_t)(r + 1) * QKV_STRIDE + lane] : 0.f;
        float s0 = q * kp, s1 = q * km, s2 = q * kn;
#pragma unroll
        for (int off = 32; off > 0; off >>= 1) {
            s0 += __shfl_xor(s0, off);
            s1 += __shfl_xor(s1, off);
            s2 += __shfl_xor(s2, off);
        }
        const float m  = fmaxf(fmaxf(s0, s1), fmaxf(s2, 0.f));
        const float e0 = __expf(s0 - m);
        const float e1 = __expf(s1 - m);
        const float e2 = __expf(s2 - m);
        const float eb = __expf(-m);
        const float rd = 1.f / (e0 + e1 + e2 + (float)(NSEQ - 3) * eb);
        const float o  = (e0 * v0 + e1 * v1 + e2 * v2 + eb * vs) * rd;
        AObh[(size_t)r * EMBED + lane] = f2bf(o);
    }
}

extern "C" void kernel_launch(void* const* d_in, const int* in_sizes, int n_in,
                              void* d_out, int out_size, void* d_ws, size_t ws_size,
                              hipStream_t stream)
{
    const float* x  = (const float*)d_in[0];
    const float* Wq = (const float*)d_in[1];
    const float* bq = (const float*)d_in[2];
    const float* Wk = (const float*)d_in[3];
    const float* bk = (const float*)d_in[4];
    const float* Wv = (const float*)d_in[5];
    const float* bv = (const float*)d_in[6];
    const float* Wo = (const float*)d_in[7];
    const float* bo = (const float*)d_in[8];
    float* out = (float*)d_out;

    // ws layout (31.6 MB total; AOb aliases xb — xb dead after gemm_qkv)
    float* QKV  = (float*)d_ws;                                // 6291456 f
    u16*   xb   = (u16*)(QKV + (size_t)NROWS * QKV_STRIDE);    // 2097152 bf16
    u16*   AOb  = xb;                                          // alias
    u16*   Wcat = xb + XELEMS;                                 // 786432
    u16*   Wob  = Wcat + WCATELEMS;                            // 262144
    float* vpart = (float*)(Wob + WOELEMS);                    // 32768 f

    const int prep_blocks = (XELEMS + WCATELEMS + WOELEMS) / 8 / 256;  // 1536
    prep_kernel<<<prep_blocks, 256, 0, stream>>>(x, Wq, Wk, Wv, Wo, xb, Wcat, Wob);
    gemm_qkv_mfma<<<dim3(32, 12), 256, 0, stream>>>(xb, Wcat, bq, bk, bv, QKV);
    vsum_part<<<dim3(16, 8), 256, 0, stream>>>(QKV, vpart);
    attn_kernel<<<dim3(16, 128), 256, 0, stream>>>(QKV, vpart, AOb);
    gemm_out_mfma<<<dim3(32, 4), 256, 0, stream>>>(AOb, Wob, bo, out);
}

// Round 3
// 114.018 us; speedup vs baseline: 1.9664x; 1.0870x over previous
//
#include <hip/hip_runtime.h>
#include <hip/hip_bf16.h>

#define EMBED 512
#define NH 8
#define DH 64
#define NSEQ 2048
#define BATCH 2
#define NROWS (BATCH * NSEQ)     // 4096
#define QKV_STRIDE 1536

typedef unsigned short u16;
typedef __bf16 bf16x8 __attribute__((ext_vector_type(8)));
typedef float f32x4 __attribute__((ext_vector_type(4)));

__device__ __forceinline__ u16 f2bf(float f) {
    unsigned u = __float_as_uint(f);
    unsigned r = (u + 0x7FFFu + ((u >> 16) & 1u)) >> 16;
    return (u16)r;
}

// ---------------------------------------------------------------------------
// prep: x -> xb (bf16), Wq|Wk|Wv -> Wcat[1536][512] bf16, Wo -> Wob bf16.
// ---------------------------------------------------------------------------
#define XELEMS   (NROWS * EMBED)          // 2097152
#define WCATELEMS (1536 * EMBED)          // 786432
#define WOELEMS  (EMBED * EMBED)          // 262144

__global__ __launch_bounds__(256) void prep_kernel(
    const float* __restrict__ x,
    const float* __restrict__ Wq, const float* __restrict__ Wk,
    const float* __restrict__ Wv, const float* __restrict__ Wo,
    u16* __restrict__ xb, u16* __restrict__ Wcat, u16* __restrict__ Wob)
{
    const long long e0 = (long long)(blockIdx.x * 256 + threadIdx.x) * 8;
    const float* src;
    u16* dst;
    if (e0 < XELEMS) {
        src = x + e0; dst = xb + e0;
    } else if (e0 < XELEMS + WCATELEMS) {
        const long long j = e0 - XELEMS;
        const int row = (int)(j >> 9);
        const int col = (int)(j & 511);
        const int sel = row >> 9;            // 0:Wq 1:Wk 2:Wv
        const int r   = row & 511;
        const float* W = (sel == 0) ? Wq : (sel == 1) ? Wk : Wv;
        src = W + (size_t)r * EMBED + col; dst = Wcat + j;
    } else {
        const long long j = e0 - XELEMS - WCATELEMS;
        src = Wo + j; dst = Wob + j;
    }
    float4 a = *(const float4*)(src);
    float4 b = *(const float4*)(src + 4);
    union { u16 u[8]; uint4 v; } p;
    p.u[0] = f2bf(a.x); p.u[1] = f2bf(a.y); p.u[2] = f2bf(a.z); p.u[3] = f2bf(a.w);
    p.u[4] = f2bf(b.x); p.u[5] = f2bf(b.y); p.u[6] = f2bf(b.z); p.u[7] = f2bf(b.w);
    *(uint4*)(dst) = p.v;
}

// ---------------------------------------------------------------------------
// 128x128 bf16 MFMA tile (m97 structure). Optional per-column-sum epilogue
// (for the V tile): vpartial[col_local * 32 + mblock] = sum over the 128
// rows of this block's (pre-bias) output tile.
// ---------------------------------------------------------------------------
__device__ __forceinline__ void gemm_tile_128(
    const u16* __restrict__ A, const u16* __restrict__ W,
    const float* __restrict__ bias,
    float* __restrict__ C, int ldc, int m0, int n0w, int n0c,
    float* __restrict__ vpartial, int mblock)
{
    __shared__ u16 As[128 * 32];
    __shared__ u16 Bs[128 * 32];
    __shared__ float csum[2][128];

    const int t    = threadIdx.x;
    const int wave = t >> 6, lane = t & 63;
    const int wm   = wave >> 1, wn = wave & 1;
    const int qd   = lane >> 4, lr = lane & 15;

    f32x4 acc[4][4] = {};

    const u16* Ag = A + (size_t)m0 * EMBED;
    const u16* Wg = W + (size_t)n0w * EMBED;
    const int srow = t >> 2;
    const int sk   = (t & 3) * 8;

    u16* AsW0 = As + (size_t)(wave * 64) * 8;
    u16* AsW1 = As + (size_t)(256 + wave * 64) * 8;
    u16* BsW0 = Bs + (size_t)(wave * 64) * 8;
    u16* BsW1 = Bs + (size_t)(256 + wave * 64) * 8;

    for (int kc = 0; kc < EMBED; kc += 32) {
        __builtin_amdgcn_global_load_lds(
            (const __attribute__((address_space(1))) void*)(Ag + (size_t)srow * EMBED + kc + sk),
            (__attribute__((address_space(3))) void*)AsW0, 16, 0, 0);
        __builtin_amdgcn_global_load_lds(
            (const __attribute__((address_space(1))) void*)(Ag + (size_t)(srow + 64) * EMBED + kc + sk),
            (__attribute__((address_space(3))) void*)AsW1, 16, 0, 0);
        __builtin_amdgcn_global_load_lds(
            (const __attribute__((address_space(1))) void*)(Wg + (size_t)srow * EMBED + kc + sk),
            (__attribute__((address_space(3))) void*)BsW0, 16, 0, 0);
        __builtin_amdgcn_global_load_lds(
            (const __attribute__((address_space(1))) void*)(Wg + (size_t)(srow + 64) * EMBED + kc + sk),
            (__attribute__((address_space(3))) void*)BsW1, 16, 0, 0);
        __syncthreads();

        bf16x8 af[4], bfr[4];
#pragma unroll
        for (int i = 0; i < 4; ++i) {
            af[i]  = *(const bf16x8*)&As[(wm * 64 + i * 16 + lr) * 32 + qd * 8];
            bfr[i] = *(const bf16x8*)&Bs[(wn * 64 + i * 16 + lr) * 32 + qd * 8];
        }
#pragma unroll
        for (int mi = 0; mi < 4; ++mi)
#pragma unroll
            for (int ni = 0; ni < 4; ++ni)
                acc[mi][ni] = __builtin_amdgcn_mfma_f32_16x16x32_bf16(
                    af[mi], bfr[ni], acc[mi][ni], 0, 0, 0);
        __syncthreads();
    }

    // C/D layout: col=lane&15, row=(lane>>4)*4+reg
#pragma unroll
    for (int ni = 0; ni < 4; ++ni) {
        const int cl = wn * 64 + ni * 16 + lr;
        const float bv = bias[cl];
        const int col = n0c + cl;
#pragma unroll
        for (int mi = 0; mi < 4; ++mi) {
#pragma unroll
            for (int e = 0; e < 4; ++e) {
                const int row = m0 + wm * 64 + mi * 16 + qd * 4 + e;
                C[(size_t)row * ldc + col] = acc[mi][ni][e] + bv;
            }
        }
    }

    if (vpartial) {
        // per-lane: sum acc over this wave's 16 rows in its qd quadrant,
        // then shfl-reduce across qd, then LDS-reduce across wm.
#pragma unroll
        for (int ni = 0; ni < 4; ++ni) {
            float s = 0.f;
#pragma unroll
            for (int mi = 0; mi < 4; ++mi)
#pragma unroll
                for (int e = 0; e < 4; ++e) s += acc[mi][ni][e];
            s += __shfl_xor(s, 16);
            s += __shfl_xor(s, 32);
            if (qd == 0) csum[wm][wn * 64 + ni * 16 + lr] = s;
        }
        __syncthreads();
        if (t < 128)
            vpartial[(size_t)t * 32 + mblock] = csum[0][t] + csum[1][t];
    }
}

// QKV GEMM: grid (32, 12). n-blocks 8..11 are the V tile -> colsum epilogue.
__global__ __launch_bounds__(256) void gemm_qkv_mfma(
    const u16* __restrict__ xb, const u16* __restrict__ Wcat,
    const float* __restrict__ bq, const float* __restrict__ bk,
    const float* __restrict__ bv, float* __restrict__ QKV,
    float* __restrict__ vpart2)
{
    const int m0 = blockIdx.x * 128;
    const int n0 = blockIdx.y * 128;
    const int sel = n0 >> 9;
    const float* bias = ((sel == 0) ? bq : (sel == 1) ? bk : bv) + (n0 & 511);
    float* vp = (sel == 2) ? (vpart2 + (size_t)(n0 - 1024) * 32) : nullptr;
    gemm_tile_128(xb, Wcat, bias, QKV, QKV_STRIDE, m0, n0, n0, vp, blockIdx.x);
}

// ---------------------------------------------------------------------------
// 128x64 bf16 MFMA tile for the output GEMM (256 blocks -> full CU fill).
// ---------------------------------------------------------------------------
__global__ __launch_bounds__(256) void gemm_out_mfma(
    const u16* __restrict__ A, const u16* __restrict__ W,
    const float* __restrict__ bo, float* __restrict__ C)
{
    __shared__ u16 As[128 * 32];
    __shared__ u16 Bs[64 * 32];

    const int m0 = blockIdx.x * 128;
    const int n0 = blockIdx.y * 64;

    const int t    = threadIdx.x;
    const int wave = t >> 6, lane = t & 63;
    const int wm   = wave >> 1, wn = wave & 1;
    const int qd   = lane >> 4, lr = lane & 15;

    f32x4 acc[4][2] = {};

    const u16* Ag = A + (size_t)m0 * EMBED;
    const u16* Wg = W + (size_t)n0 * EMBED;
    const int srow = t >> 2;
    const int sk   = (t & 3) * 8;

    u16* AsW0 = As + (size_t)(wave * 64) * 8;
    u16* AsW1 = As + (size_t)(256 + wave * 64) * 8;
    u16* BsW0 = Bs + (size_t)(wave * 64) * 8;

    for (int kc = 0; kc < EMBED; kc += 32) {
        __builtin_amdgcn_global_load_lds(
            (const __attribute__((address_space(1))) void*)(Ag + (size_t)srow * EMBED + kc + sk),
            (__attribute__((address_space(3))) void*)AsW0, 16, 0, 0);
        __builtin_amdgcn_global_load_lds(
            (const __attribute__((address_space(1))) void*)(Ag + (size_t)(srow + 64) * EMBED + kc + sk),
            (__attribute__((address_space(3))) void*)AsW1, 16, 0, 0);
        __builtin_amdgcn_global_load_lds(
            (const __attribute__((address_space(1))) void*)(Wg + (size_t)srow * EMBED + kc + sk),
            (__attribute__((address_space(3))) void*)BsW0, 16, 0, 0);
        __syncthreads();

        bf16x8 af[4], bfr[2];
#pragma unroll
        for (int i = 0; i < 4; ++i)
            af[i]  = *(const bf16x8*)&As[(wm * 64 + i * 16 + lr) * 32 + qd * 8];
#pragma unroll
        for (int i = 0; i < 2; ++i)
            bfr[i] = *(const bf16x8*)&Bs[(wn * 32 + i * 16 + lr) * 32 + qd * 8];
#pragma unroll
        for (int mi = 0; mi < 4; ++mi)
#pragma unroll
            for (int ni = 0; ni < 2; ++ni)
                acc[mi][ni] = __builtin_amdgcn_mfma_f32_16x16x32_bf16(
                    af[mi], bfr[ni], acc[mi][ni], 0, 0, 0);
        __syncthreads();
    }

#pragma unroll
    for (int ni = 0; ni < 2; ++ni) {
        const int cl = wn * 32 + ni * 16 + lr;
        const float bv = bo[n0 + cl];
#pragma unroll
        for (int mi = 0; mi < 4; ++mi) {
#pragma unroll
            for (int e = 0; e < 4; ++e) {
                const int row = m0 + wm * 64 + mi * 16 + qd * 4 + e;
                C[(size_t)row * EMBED + n0 + cl] = acc[mi][ni][e] + bv;
            }
        }
    }
}

// ---------------------------------------------------------------------------
// Attention: wave per 4 rows. lane = d. grid (16, 128), block 256.
// vs reconstructed from gemm-epilogue partials + analytic bias term.
// ---------------------------------------------------------------------------
__global__ __launch_bounds__(256) void attn_kernel(
    const float* __restrict__ QKV, const float* __restrict__ vpart2,
    const float* __restrict__ bvv, u16* __restrict__ AOb)
{
    const int bh = blockIdx.x;
    const int b = bh >> 3, h = bh & 7;
    const int wave = threadIdx.x >> 6, lane = threadIdx.x & 63;

    const float* Qb = QKV + (size_t)(b * NSEQ) * QKV_STRIDE + h * DH;
    const float* Kb = Qb + 512;
    const float* Vb = Qb + 1024;

    const float v0 = Vb[(size_t)0 * QKV_STRIDE + lane];
    const float v1 = Vb[(size_t)1 * QKV_STRIDE + lane];
    const float v2 = Vb[(size_t)2 * QKV_STRIDE + lane];

    const int c = h * DH + lane;          // V column 0..511
    float vs = 0.f;
#pragma unroll
    for (int mb = 0; mb < 16; ++mb)
        vs += vpart2[(size_t)c * 32 + b * 16 + mb];
    vs += (float)NSEQ * bvv[c];           // bias contribution of all rows
    vs -= (v0 + v1 + v2);                 // tail = sum_{j>=3}

    u16* AObh = AOb + (size_t)(b * NSEQ) * EMBED + h * DH;
    const int r0 = blockIdx.y * 16 + wave * 4;

#pragma unroll
    for (int i = 0; i < 4; ++i) {
        const int r = r0 + i;
        const float q  = Qb[(size_t)r * QKV_STRIDE + lane];
        const float km = Kb[(size_t)r * QKV_STRIDE + lane];
        const float kp = (r > 0)        ? Kb[(size_t)(r - 1) * QKV_STRIDE + lane] : 0.f;
        const float kn = (r < NSEQ - 1) ? Kb[(size_t)(r + 1) * QKV_STRIDE + lane] : 0.f;
        float s0 = q * kp, s1 = q * km, s2 = q * kn;
#pragma unroll
        for (int off = 32; off > 0; off >>= 1) {
            s0 += __shfl_xor(s0, off);
            s1 += __shfl_xor(s1, off);
            s2 += __shfl_xor(s2, off);
        }
        const float m  = fmaxf(fmaxf(s0, s1), fmaxf(s2, 0.f));
        const float e0 = __expf(s0 - m);
        const float e1 = __expf(s1 - m);
        const float e2 = __expf(s2 - m);
        const float eb = __expf(-m);
        const float rd = 1.f / (e0 + e1 + e2 + (float)(NSEQ - 3) * eb);
        const float o  = (e0 * v0 + e1 * v1 + e2 * v2 + eb * vs) * rd;
        AObh[(size_t)r * EMBED + lane] = f2bf(o);
    }
}

extern "C" void kernel_launch(void* const* d_in, const int* in_sizes, int n_in,
                              void* d_out, int out_size, void* d_ws, size_t ws_size,
                              hipStream_t stream)
{
    const float* x  = (const float*)d_in[0];
    const float* Wq = (const float*)d_in[1];
    const float* bq = (const float*)d_in[2];
    const float* Wk = (const float*)d_in[3];
    const float* bk = (const float*)d_in[4];
    const float* Wv = (const float*)d_in[5];
    const float* bv = (const float*)d_in[6];
    const float* Wo = (const float*)d_in[7];
    const float* bo = (const float*)d_in[8];
    float* out = (float*)d_out;

    float* QKV  = (float*)d_ws;                                // 6291456 f
    u16*   xb   = (u16*)(QKV + (size_t)NROWS * QKV_STRIDE);    // 2097152 bf16
    u16*   AOb  = xb;                                          // alias (xb dead after gemm_qkv)
    u16*   Wcat = xb + XELEMS;                                 // 786432
    u16*   Wob  = Wcat + WCATELEMS;                            // 262144
    float* vpart2 = (float*)(Wob + WOELEMS);                   // 512*32 f

    const int prep_blocks = (XELEMS + WCATELEMS + WOELEMS) / 8 / 256;  // 1536
    prep_kernel<<<prep_blocks, 256, 0, stream>>>(x, Wq, Wk, Wv, Wo, xb, Wcat, Wob);
    gemm_qkv_mfma<<<dim3(32, 12), 256, 0, stream>>>(xb, Wcat, bq, bk, bv, QKV, vpart2);
    attn_kernel<<<dim3(16, 128), 256, 0, stream>>>(QKV, vpart2, bv, AOb);
    gemm_out_mfma<<<dim3(32, 8), 256, 0, stream>>>(AOb, Wob, bo, out);
}